// Round 8
// baseline (23.918 us; speedup 1.0000x reference)
//
#include <hip/hip_runtime.h>

// JSSP dynamic embedding update. f32 in / f32 out.
// Shapes: bs=128, M=64, O=4096, J=64, E=256. SCALE=1000.
// For job j of batch b, o = next_op[b,j]:
//   a = max(lbs[b,o]-time[b],0)/1000 ; r = is_ready[b,o]
//   acc[e] = sum_m [busy[b,m]>time[b] ? 0 : proc[b,m,o]/1000] * emb[b,m,e]
//   out_k[b,j,e] = a*Wn[0,k*256+e] + r*Wn[1,k*256+e] + We[k]*acc[e]
//
// v8: (2 j, 4 e) per thread. Cuts LDS broadcast delivery 4x (32 ds_read_b128
// per thread instead of 128; each feeds 16 FMAs), emb loads become coalesced
// float4 (L1 absorbs the 4x cross-wave duplication), stores become dwordx4.
// Theory: LDS delivery was ~48% of CU cycles, co-bottleneck with HBM.

#define BS 128
#define MM 64
#define OO 4096
#define JJ 64
#define EE 256
#define JH 8     // jobs per block (8 blocks per batch)
#define SP 68    // padded LDS row; 272B rows stay 16B-aligned

__global__ __launch_bounds__(256, 4) void jssp_kernel(
    const float* __restrict__ lbs,       // [BS,OO]
    const float* __restrict__ time_,     // [BS]
    const float* __restrict__ isr,       // [BS,OO]
    const float* __restrict__ proc,      // [BS,MM,OO]
    const float* __restrict__ busy,      // [BS,MM]
    const float* __restrict__ emb,       // [BS,MM,EE]
    const float* __restrict__ Wn,        // [2,768]
    const float* __restrict__ We,        // [3]
    const int*   __restrict__ nop,       // [BS,JJ]
    float* __restrict__ out)             // 3 x [BS,JJ,EE] concatenated, f32
{
    __shared__ float S[JH][SP];
    __shared__ float aj[JH], rj[JH];

    // XCD-aware bijective remap (8 XCDs, grid 1024 % 8 == 0):
    const int hw  = blockIdx.x;
    const int xcd = hw & 7;
    const int k   = hw >> 3;
    const int b   = xcd * 16 + (k >> 3);
    const int jh  = k & 7;
    const int t   = threadIdx.x;
    const int el  = t & 63;        // e-quad: e = 4*el .. 4*el+3
    const int jl  = t >> 6;        // wave id; owns jobs {2jl, 2jl+1}
    const float tb = time_[b];

    // ---- scattered proc gather, 2/thread (wave instr = 8 rows x 8 jobs) ----
    float gv[2], gbz[2];
    int   gjj[2], gm[2];
    #pragma unroll
    for (int it = 0; it < 2; ++it) {
        const int id = it * 256 + t;
        const int jj = id & 7;
        const int m  = id >> 3;
        const int o  = nop[b * JJ + jh * JH + jj];
        gjj[it] = jj; gm[it] = m;
        gv[it]  = proc[(size_t)(b * MM + m) * OO + (size_t)o];
        gbz[it] = busy[b * MM + m];
    }

    float al = 0.0f, rl = 0.0f;
    if (t < JH) {
        const int o = nop[b * JJ + jh * JH + t];
        al = lbs[b * OO + o];
        rl = isr[b * OO + o];
    }

    // emb base for this thread's e-quad; prefetch m-chunk 0 pre-barrier.
    const float* embB = emb + (size_t)(b * MM) * EE + (size_t)(el * 4);
    float4 ea0 = *(const float4*)(embB + 0 * EE);
    float4 ea1 = *(const float4*)(embB + 1 * EE);
    float4 ea2 = *(const float4*)(embB + 2 * EE);
    float4 ea3 = *(const float4*)(embB + 3 * EE);
    float4 eb0, eb1, eb2, eb3;

    // LDS writes, single barrier:
    #pragma unroll
    for (int it = 0; it < 2; ++it)
        S[gjj[it]][gm[it]] = (gbz[it] > tb) ? 0.0f : gv[it] * 1e-3f;
    if (t < JH) {
        aj[t] = fmaxf(al - tb, 0.0f) * 1e-3f;
        rj[t] = rl;
    }
    __syncthreads();

    const int j0 = jl * 2;
    const float4* S4A = reinterpret_cast<const float4*>(&S[j0][0]);
    const float4* S4B = reinterpret_cast<const float4*>(&S[j0 + 1][0]);

    float4 accA; accA.x = accA.y = accA.z = accA.w = 0.0f;
    float4 accB; accB.x = accB.y = accB.z = accB.w = 0.0f;

#define FMA4(ACC, SS, EV)                         \
    ACC.x = fmaf(SS, EV.x, ACC.x);                \
    ACC.y = fmaf(SS, EV.y, ACC.y);                \
    ACC.z = fmaf(SS, EV.z, ACC.z);                \
    ACC.w = fmaf(SS, EV.w, ACC.w);

#define CHUNK(SA, SB, E0, E1, E2, E3)             \
    FMA4(accA, SA.x, E0) FMA4(accA, SA.y, E1)     \
    FMA4(accA, SA.z, E2) FMA4(accA, SA.w, E3)     \
    FMA4(accB, SB.x, E0) FMA4(accB, SB.y, E1)     \
    FMA4(accB, SB.z, E2) FMA4(accB, SB.w, E3)

    // 16 m-chunks of 4; static ping-pong ea<->eb (rule #20: all names static)
    #pragma unroll
    for (int cc = 0; cc < 8; ++cc) {
        const int c0 = 2 * cc, c1 = 2 * cc + 1;
        eb0 = *(const float4*)(embB + (size_t)(c1 * 4 + 0) * EE);
        eb1 = *(const float4*)(embB + (size_t)(c1 * 4 + 1) * EE);
        eb2 = *(const float4*)(embB + (size_t)(c1 * 4 + 2) * EE);
        eb3 = *(const float4*)(embB + (size_t)(c1 * 4 + 3) * EE);
        {
            const float4 sA = S4A[c0], sB = S4B[c0];
            CHUNK(sA, sB, ea0, ea1, ea2, ea3)
        }
        if (cc < 7) {
            const int cn = 2 * cc + 2;
            ea0 = *(const float4*)(embB + (size_t)(cn * 4 + 0) * EE);
            ea1 = *(const float4*)(embB + (size_t)(cn * 4 + 1) * EE);
            ea2 = *(const float4*)(embB + (size_t)(cn * 4 + 2) * EE);
            ea3 = *(const float4*)(embB + (size_t)(cn * 4 + 3) * EE);
        }
        {
            const float4 sA = S4A[c1], sB = S4B[c1];
            CHUNK(sA, sB, eb0, eb1, eb2, eb3)
        }
    }
#undef CHUNK
#undef FMA4

    // ---- epilogue: 6 float4 stores ----
    const float a0 = aj[j0],     r0 = rj[j0];
    const float a1 = aj[j0 + 1], r1 = rj[j0 + 1];
    const float we0 = We[0], we1 = We[1], we2 = We[2];
    const float4 w0a = *(const float4*)(Wn + el * 4);
    const float4 w1a = *(const float4*)(Wn + 768 + el * 4);
    const float4 w0b = *(const float4*)(Wn + 256 + el * 4);
    const float4 w1b = *(const float4*)(Wn + 1024 + el * 4);
    const float4 w0c = *(const float4*)(Wn + 512 + el * 4);
    const float4 w1c = *(const float4*)(Wn + 1280 + el * 4);

    auto epi = [](float A, float R, const float4& ACC, const float4& W0,
                  const float4& W1, float WE) {
        float4 v;
        v.x = fmaf(A, W0.x, fmaf(R, W1.x, WE * ACC.x));
        v.y = fmaf(A, W0.y, fmaf(R, W1.y, WE * ACC.y));
        v.z = fmaf(A, W0.z, fmaf(R, W1.z, WE * ACC.z));
        v.w = fmaf(A, W0.w, fmaf(R, W1.w, WE * ACC.w));
        return v;
    };

    const size_t SZ   = (size_t)BS * JJ * EE;                  // 2097152
    const size_t base = (size_t)(b * JJ + jh * JH) * EE + (size_t)(el * 4);

    *(float4*)(out + base + (size_t)j0 * EE)             = epi(a0, r0, accA, w0a, w1a, we0);
    *(float4*)(out + base + (size_t)(j0 + 1) * EE)       = epi(a1, r1, accB, w0a, w1a, we0);
    *(float4*)(out + SZ + base + (size_t)j0 * EE)        = epi(a0, r0, accA, w0b, w1b, we1);
    *(float4*)(out + SZ + base + (size_t)(j0 + 1) * EE)  = epi(a1, r1, accB, w0b, w1b, we1);
    *(float4*)(out + 2 * SZ + base + (size_t)j0 * EE)    = epi(a0, r0, accA, w0c, w1c, we2);
    *(float4*)(out + 2 * SZ + base + (size_t)(j0 + 1) * EE) = epi(a1, r1, accB, w0c, w1c, we2);
}

extern "C" void kernel_launch(void* const* d_in, const int* in_sizes, int n_in,
                              void* d_out, int out_size, void* d_ws, size_t ws_size,
                              hipStream_t stream) {
    const float* lbs   = (const float*)d_in[0];
    const float* time_ = (const float*)d_in[1];
    const float* isr   = (const float*)d_in[2];
    const float* proc  = (const float*)d_in[3];
    const float* busy  = (const float*)d_in[4];
    const float* emb   = (const float*)d_in[5];
    const float* Wn    = (const float*)d_in[6];
    const float* We    = (const float*)d_in[7];
    const int*   nop   = (const int*)d_in[8];
    float* out = (float*)d_out;

    jssp_kernel<<<dim3(BS * (JJ / JH)), dim3(256), 0, stream>>>(
        lbs, time_, isr, proc, busy, emb, Wn, We, nop, out);
}

// Round 9
// 21.138 us; speedup vs baseline: 1.1315x; 1.1315x over previous
//
#include <hip/hip_runtime.h>

// JSSP dynamic embedding update. f32 in / f32 out.
// Shapes: bs=128, M=64, O=4096, J=64, E=256. SCALE=1000.
// For job j of batch b, o = next_op[b,j]:
//   a = max(lbs[b,o]-time[b],0)/1000 ; r = is_ready[b,o]
//   acc[e] = sum_m [busy[b,m]>time[b] ? 0 : proc[b,m,o]/1000] * emb[b,m,e]
//   out_k[b,j,e] = a*Wn[0,k*256+e] + r*Wn[1,k*256+e] + We[k]*acc[e]
//
// v9 == v7 (measured best, 21.27us): thread = one e-column (emb loaded
// exactly once per block, coalesced dwords), LDS S[8][68] broadcast reads
// (uniform-address = free), single barrier, XCD-aware sibling remap,
// chunked emb ping-pong staging, 24 waves/CU cap.
// v8's (2j,4e) remap regressed (4x emb duplication through L1/L2).
// Plateau evidence (22.0/21.9/21.3/23.9) -> scatter-bound floor:
// proc gather = 2MB useful data amplified to 30-53MB of 64-128B lines.

#define BS 128
#define MM 64
#define OO 4096
#define JJ 64
#define EE 256
#define JH 8     // jobs per block (8 blocks per batch)
#define SP 68    // padded LDS row (16B-aligned rows, conflict-light writes)

__global__ __launch_bounds__(256, 6) void jssp_kernel(
    const float* __restrict__ lbs,       // [BS,OO]
    const float* __restrict__ time_,     // [BS]
    const float* __restrict__ isr,       // [BS,OO]
    const float* __restrict__ proc,      // [BS,MM,OO]
    const float* __restrict__ busy,      // [BS,MM]
    const float* __restrict__ emb,       // [BS,MM,EE]
    const float* __restrict__ Wn,        // [2,768]
    const float* __restrict__ We,        // [3]
    const int*   __restrict__ nop,       // [BS,JJ]
    float* __restrict__ out)             // 3 x [BS,JJ,EE] concatenated, f32
{
    __shared__ float S[JH][SP];
    __shared__ float aj[JH], rj[JH];

    // XCD-aware bijective remap (8 XCDs, grid 1024 % 8 == 0):
    const int hw  = blockIdx.x;
    const int xcd = hw & 7;
    const int k   = hw >> 3;
    const int b   = xcd * 16 + (k >> 3);
    const int jh  = k & 7;
    const int t   = threadIdx.x;          // 0..255 == e
    const float tb = time_[b];

    // ---- proc gather: 2/thread; wave-instr covers 8 rows x 8 jobs ----
    float gv[2], gbz[2];
    int   gjj[2], gm[2];
    #pragma unroll
    for (int it = 0; it < 2; ++it) {
        const int id = it * 256 + t;
        const int jj = id & 7;            // 0..7
        const int m  = id >> 3;           // 0..63
        const int o  = nop[b * JJ + jh * JH + jj];
        gjj[it] = jj; gm[it] = m;
        gv[it]  = proc[(size_t)(b * MM + m) * OO + (size_t)o];
        gbz[it] = busy[b * MM + m];
    }

    // aj/rj gathers (8 lanes of wave 0):
    float al = 0.0f, rl = 0.0f;
    if (t < JH) {
        const int o = nop[b * JJ + jh * JH + t];
        al = lbs[b * OO + o];
        rl = isr[b * OO + o];
    }

    // node-linear constants (column e of the three E-slices):
    const float w0a = Wn[t],            w1a = Wn[768 + t];
    const float w0b = Wn[EE + t],       w1b = Wn[768 + EE + t];
    const float w0c = Wn[2 * EE + t],   w1c = Wn[768 + 2 * EE + t];
    const float we0 = We[0], we1 = We[1], we2 = We[2];

    // emb chunks 0,1 prefetch BEFORE the barrier (independent of LDS):
    const size_t ebase = (size_t)(b * MM) * EE + (size_t)t;
    float eA[16], eB[16];
    #pragma unroll
    for (int i = 0; i < 16; ++i) eA[i] = emb[ebase + (size_t)i * EE];
    #pragma unroll
    for (int i = 0; i < 16; ++i) eB[i] = emb[ebase + (size_t)(16 + i) * EE];

    // LDS writes, single barrier:
    #pragma unroll
    for (int it = 0; it < 2; ++it)
        S[gjj[it]][gm[it]] = (gbz[it] > tb) ? 0.0f : gv[it] * 1e-3f;
    if (t < JH) {
        aj[t] = fmaxf(al - tb, 0.0f) * 1e-3f;
        rj[t] = rl;
    }
    __syncthreads();

    float acc[JH];
    #pragma unroll
    for (int j = 0; j < JH; ++j) acc[j] = 0.0f;

    #define COMP(EREG, C)                                                  \
        _Pragma("unroll")                                                  \
        for (int j = 0; j < JH; ++j) {                                     \
            const float4* S4 = reinterpret_cast<const float4*>(&S[j][(C) * 16]); \
            _Pragma("unroll")                                              \
            for (int m4 = 0; m4 < 4; ++m4) {                               \
                const float4 s = S4[m4];                                   \
                acc[j] = fmaf(s.x, EREG[4 * m4 + 0], acc[j]);              \
                acc[j] = fmaf(s.y, EREG[4 * m4 + 1], acc[j]);              \
                acc[j] = fmaf(s.z, EREG[4 * m4 + 2], acc[j]);              \
                acc[j] = fmaf(s.w, EREG[4 * m4 + 3], acc[j]);              \
            }                                                              \
        }

    COMP(eA, 0);
    #pragma unroll
    for (int i = 0; i < 16; ++i) eA[i] = emb[ebase + (size_t)(32 + i) * EE];
    COMP(eB, 1);
    #pragma unroll
    for (int i = 0; i < 16; ++i) eB[i] = emb[ebase + (size_t)(48 + i) * EE];
    COMP(eA, 2);
    COMP(eB, 3);
    #undef COMP

    // ---- epilogue: stores grouped by output segment ----
    const size_t SZ   = (size_t)BS * JJ * EE;                 // 2097152
    const size_t base = (size_t)(b * JJ + jh * JH) * EE + (size_t)t;

    #pragma unroll
    for (int j = 0; j < JH; ++j)
        out[base + (size_t)j * EE] =
            fmaf(aj[j], w0a, fmaf(rj[j], w1a, we0 * acc[j]));
    #pragma unroll
    for (int j = 0; j < JH; ++j)
        out[SZ + base + (size_t)j * EE] =
            fmaf(aj[j], w0b, fmaf(rj[j], w1b, we1 * acc[j]));
    #pragma unroll
    for (int j = 0; j < JH; ++j)
        out[2 * SZ + base + (size_t)j * EE] =
            fmaf(aj[j], w0c, fmaf(rj[j], w1c, we2 * acc[j]));
}

extern "C" void kernel_launch(void* const* d_in, const int* in_sizes, int n_in,
                              void* d_out, int out_size, void* d_ws, size_t ws_size,
                              hipStream_t stream) {
    const float* lbs   = (const float*)d_in[0];
    const float* time_ = (const float*)d_in[1];
    const float* isr   = (const float*)d_in[2];
    const float* proc  = (const float*)d_in[3];
    const float* busy  = (const float*)d_in[4];
    const float* emb   = (const float*)d_in[5];
    const float* Wn    = (const float*)d_in[6];
    const float* We    = (const float*)d_in[7];
    const int*   nop   = (const int*)d_in[8];
    float* out = (float*)d_out;

    jssp_kernel<<<dim3(BS * (JJ / JH)), dim3(256), 0, stream>>>(
        lbs, time_, isr, proc, busy, emb, Wn, We, nop, out);
}